// Round 23
// baseline (73.947 us; speedup 1.0000x reference)
//
#include <hip/hip_runtime.h>
#include <cmath>
#include <complex>

// sr=16000, band 500-7000, order 8 -> 16 poles = 8 real 2nd-order sections.
#define NB    32
#define LX    262144
#define PAD   51                      // padlen = 3*17
#define LTOT  (LX + 2 * PAD)          // 262246
#define CM    16                      // samples per chunk (= per lane)
#define F_PAD 1946                    // zero-input front pad
#define LPAD  (LTOT + F_PAD)          // 264192 = 258 * 1024 (tile-aligned)
#define TILE  (64 * CM)               // 1024 samples per wave-tile
#define NTILE (LPAD / TILE)           // 258 wave-tiles per row
#define WPB   4                       // wave-tiles per 256-thread block
#define NBX   ((NTILE + WPB - 1) / WPB)  // 65 blocks per row (last: 2 idle waves)
#define NP    8
#define LDSR  17                      // floats per LDS lane-row (gcd(17,32)=1)
#define WIN   16                      // window (chunks) = 256 samples (validated)
#define WREG  1088                    // floats per wave LDS region (4352 B)

struct CoeffsS { float a1[NP], a2[NP], b0[NP], b1[NP], c0; };
// lv[k][q] = (A_q^16)^(2^k) = M0^(2^k), k=0..5; scan uses lv[0..3]
struct LvS { float lv[6][NP][4]; };

// wave-private LDS sync (r22-verified): lgkmcnt(0) + wave64 lockstep.
__device__ __forceinline__ void wave_sync() {
    asm volatile("s_waitcnt lgkmcnt(0)" ::: "memory");
}

// ---------------------------------------------------------------------------
// init: build mt[t*8+q] = M0^t (t=0..63; edge fix uses t<=15).
__global__ void k_init(float4* __restrict__ mt, LvS L) {
    int id = blockIdx.x * 256 + threadIdx.x;
    if (id >= 512) return;
    int t = id >> 3, q = id & 7;
    float m0 = 1.f, m1 = 0.f, m2 = 0.f, m3 = 1.f;
    for (int k = 0; k < 6; k++)
        if ((t >> k) & 1) {
            float a0 = L.lv[k][q][0], a1 = L.lv[k][q][1];
            float a2 = L.lv[k][q][2], a3 = L.lv[k][q][3];
            float n0 = a0 * m0 + a1 * m2, n1 = a0 * m1 + a1 * m3;
            float n2 = a2 * m0 + a3 * m2, n3 = a2 * m1 + a3 * m3;
            m0 = n0; m1 = n1; m2 = n2; m3 = n3;
        }
    mt[id] = make_float4(m0, m1, m2, m3);
}

// ---------------------------------------------------------------------------
// u-loader pass A: chunk c covers t' = c*CM..+CM, real t = t' - F_PAD.
// Safe for negative c (all-pad -> u=0).
__device__ __forceinline__ void load_uA(const float* __restrict__ x,
                                        float base, int c, float (&u)[CM]) {
    int t0 = c * CM - F_PAD;
    if (t0 >= PAD && t0 + CM <= PAD + LX) {
        const float* xs = x + (t0 - PAD);
#pragma unroll
        for (int m = 0; m < CM / 4; m++) {
            float4 v = *reinterpret_cast<const float4*>(xs + 4 * m);
            u[4 * m] = v.x - base; u[4 * m + 1] = v.y - base;
            u[4 * m + 2] = v.z - base; u[4 * m + 3] = v.w - base;
        }
    } else {
#pragma unroll
        for (int i = 0; i < CM; i++) {
            int t = t0 + i;
            float uu;
            if (t < 0) uu = 0.f;                        // front pad
            else {
                float e;
                if (t < PAD)            e = 2.0f * x[0] - x[PAD - t];
                else if (t < PAD + LX)  e = x[t - PAD];
                else                    e = 2.0f * x[LX - 1] - x[2 * LX + PAD - 2 - t];
                uu = e - base;
            }
            u[i] = uu;
        }
    }
}

// u-loader pass B: chunk c from reversed-y buffer minus base; c<0 -> u=0.
__device__ __forceinline__ void load_uB(const float* __restrict__ yb,
                                        float base, int c, float (&u)[CM]) {
    if (c < 0) {
#pragma unroll
        for (int i = 0; i < CM; i++) u[i] = 0.f;
        return;
    }
    const float* ys = yb + (size_t)c * CM;
#pragma unroll
    for (int m = 0; m < CM / 4; m++) {
        float4 v = *reinterpret_cast<const float4*>(ys + 4 * m);
        u[4 * m] = v.x - base; u[4 * m + 1] = v.y - base;
        u[4 * m + 2] = v.z - base; u[4 * m + 3] = v.w - base;
    }
}

// local chunk recurrence from zero state
__device__ __forceinline__ void local_states(const float (&u)[CM], const CoeffsS& C,
                                             float (&w1)[NP], float (&w2)[NP]) {
#pragma unroll
    for (int q = 0; q < NP; q++) { w1[q] = 0.f; w2[q] = 0.f; }
#pragma unroll
    for (int i = 0; i < CM; i++) {
        float uu = u[i];
#pragma unroll
        for (int q = 0; q < NP; q++) {
            float wt = fmaf(C.a1[q], w1[q], fmaf(C.a2[q], w2[q], uu));
            w2[q] = w1[q]; w1[q] = wt;
        }
    }
}

// ---------------------------------------------------------------------------
// One filtfilt direction; 4 independent wave-tiles per 256-thread block.
// Entry state via 4-level shfl log-doubling window scan (256-sample window)
// + LDS edge fix from 16 warmup chunk-states (lanes l<16 only).
// PASS 0: in=audio -> ybuf reversed.  PASS 1: in=ybuf -> out (rev+trim).
template <int PASS>
__global__ __launch_bounds__(256) void k_full(const float* __restrict__ in,
                                              float* __restrict__ outp,
                                              const float4* __restrict__ mt,
                                              CoeffsS C, LvS L) {
    __shared__ __align__(16) float lds[WPB * WREG];   // 17408 B
    int tid = threadIdx.x, wv = tid >> 6, l = tid & 63;
    int ttx = blockIdx.x * WPB + wv, b = blockIdx.y;
    if (ttx >= NTILE) return;                          // tail block: idle waves
    int c = ttx * 64 + l;
    float* wlds = lds + wv * WREG;
    float4* scw = reinterpret_cast<float4*>(wlds);    // 64 float4 warmup region

    const float* x = in + (size_t)b * (PASS == 0 ? LX : LPAD);
    float base = (PASS == 0) ? (2.0f * x[0] - x[PAD]) : x[0];

    // ---- warmup: lanes<WIN compute chunk ttx*64-WIN+l; pack to LDS ----
    if (l < WIN) {
        float uw[CM];
        int cw = ttx * 64 - WIN + l;
        if (PASS == 0) load_uA(x, base, cw, uw);
        else           load_uB(x, base, cw, uw);
        float w1[NP], w2[NP];
        local_states(uw, C, w1, w2);
#pragma unroll
        for (int p = 0; p < 4; p++)
            scw[p * WIN + l] = make_float4(w1[2 * p], w2[2 * p],
                                           w1[2 * p + 1], w2[2 * p + 1]);
    }

    // ---- primary chunk: states stay in registers (g) ----
    float u[CM];
    if (PASS == 0) load_uA(x, base, c, u);
    else           load_uB(x, base, c, u);
    float g1[NP], g2[NP];
    local_states(u, C, g1, g2);

    // ---- 4-level log-doubling scan: G_l = sum_{k=0..15} M0^k f_{l-k} ----
#pragma unroll
    for (int s = 0; s < 4; s++) {
        int d = 1 << s;
#pragma unroll
        for (int q = 0; q < NP; q++) {
            float o1 = __shfl_up(g1[q], d);
            float o2 = __shfl_up(g2[q], d);
            if (l < d) { o1 = 0.f; o2 = 0.f; }
            g1[q] = fmaf(L.lv[s][q][0], o1, fmaf(L.lv[s][q][1], o2, g1[q]));
            g2[q] = fmaf(L.lv[s][q][2], o1, fmaf(L.lv[s][q][3], o2, g2[q]));
        }
    }

    // ---- entry E_l = G_{l-1} ----
    float e1[NP], e2[NP];
#pragma unroll
    for (int q = 0; q < NP; q++) {
        float a = __shfl_up(g1[q], 1), bb = __shfl_up(g2[q], 1);
        e1[q] = (l == 0) ? 0.f : a;
        e2[q] = (l == 0) ? 0.f : bb;
    }

    // ---- edge fix (lanes l<WIN): add warmup terms k=l+1..16 from LDS ----
    wave_sync();                            // warmup packs visible
    if (l < WIN) {
        for (int j = l; j < WIN; j++) {
            int km1 = WIN - 1 + l - j;      // 15+l-j, in [l, 15]
#pragma unroll
            for (int p = 0; p < 4; p++) {
                float4 fw = scw[p * WIN + j];
                float4 ma = mt[km1 * NP + 2 * p];
                float4 mb = mt[km1 * NP + 2 * p + 1];
                e1[2 * p]     = fmaf(ma.x, fw.x, fmaf(ma.y, fw.y, e1[2 * p]));
                e2[2 * p]     = fmaf(ma.z, fw.x, fmaf(ma.w, fw.y, e2[2 * p]));
                e1[2 * p + 1] = fmaf(mb.x, fw.z, fmaf(mb.y, fw.w, e1[2 * p + 1]));
                e2[2 * p + 1] = fmaf(mb.z, fw.z, fmaf(mb.w, fw.w, e2[2 * p + 1]));
            }
        }
    }

    // ---- replay u -> y with entry state (registers) ----
#pragma unroll
    for (int q = 0; q < NP; q++) { g1[q] = e1[q]; g2[q] = e2[q]; }
#pragma unroll
    for (int i = 0; i < CM; i++) {
        float uu = u[i];
        float y = C.c0 * uu;
#pragma unroll
        for (int q = 0; q < NP; q++) {
            float wt = fmaf(C.a1[q], g1[q], fmaf(C.a2[q], g2[q], uu));
            y = fmaf(C.b0[q], wt, fmaf(C.b1[q], g1[q], y));
            g2[q] = g1[q]; g1[q] = wt;
        }
        u[i] = y;                          // u now holds y
    }

    // ---- stage y to LDS (stride-17); store (r17/r22-verified mappings) ----
    wave_sync();                           // edge reads done before overwrite
#pragma unroll
    for (int i = 0; i < CM; i++) wlds[l * LDSR + i] = u[i];
    wave_sync();

    if (PASS == 0) {
        // coalesced REVERSED store of this tile's 1024 samples
        float4* yb4 = reinterpret_cast<float4*>(
            outp + (size_t)b * LPAD + (size_t)(NTILE - 1 - ttx) * TILE);
#pragma unroll
        for (int k = 0; k < 4; k++) {
            int o4 = l + 64 * k;               // 0..255
            int ts = 63 - (o4 >> 2);
            int ih = 15 - 4 * (o4 & 3);
            const float* r = &wlds[ts * LDSR];
            yb4[o4] = make_float4(r[ih], r[ih - 1], r[ih - 2], r[ih - 3]);
        }
    } else {
        // out[j] = y2[s], j = (LTOT-1-PAD) - s  (un-reverse + trim)
        float* ob = outp + (size_t)b * LX;
        int J0 = (LTOT - 1 - PAD) - ttx * TILE;
#pragma unroll
        for (int it = 0; it < CM; it++) {
            int o = it * 64 + l;
            int j = J0 - o;
            if (j >= 0 && j < LX)
                ob[j] = wlds[(o >> 4) * LDSR + (o & 15)];
        }
    }
}

// ---------------------------------------------------------------------------
// Host: scipy butter(8,[500,7000]/8000,'bandpass') -> real 2nd-order sections
// + chunk-transition (A^16) power levels (f64, cast to f32).
static void compute_coeffs(CoeffsS& C, LvS& L) {
    using cd = std::complex<double>;
    const int N = 8;
    const double sr = 16000.0, lo = 500.0, hi = 7000.0, fs = 2.0;
    double w0 = 2.0 * fs * std::tan(M_PI * (2.0 * lo / sr) / fs);
    double w1 = 2.0 * fs * std::tan(M_PI * (2.0 * hi / sr) / fs);
    double bw = w1 - w0, wo = std::sqrt(w0 * w1);
    cd pbp[16];
    for (int k = 0; k < N; k++) {
        int m = -N + 1 + 2 * k;
        cd pl = -std::exp(cd(0.0, M_PI * m / (2.0 * N)));
        pl *= bw / 2.0;
        cd s = std::sqrt(pl * pl - cd(wo * wo, 0.0));
        pbp[k] = pl + s; pbp[k + N] = pl - s;
    }
    double kbp = std::pow(bw, (double)N);
    const double fs2 = 4.0;
    cd pd[16], denom = 1.0;
    for (int i = 0; i < 16; i++) {
        pd[i] = (cd(fs2, 0.0) + pbp[i]) / (cd(fs2, 0.0) - pbp[i]);
        denom *= (cd(fs2, 0.0) - pbp[i]);
    }
    double kd = kbp * std::real(cd(std::pow(fs2, 8.0), 0.0) / denom);
    cd prodp = 1.0;
    for (int i = 0; i < 16; i++) prodp *= pd[i];
    cd c0 = cd(kd, 0.0) / prodp;
    int n = 0;
    for (int i = 0; i < 16; i++) {
        if (pd[i].imag() <= 0.0) continue;
        cd inv = 1.0 / pd[i];
        cd t1 = cd(1.0, 0.0) - inv, t2 = cd(1.0, 0.0) + inv;
        cd numr = cd(kd, 0.0);
        for (int k = 0; k < 8; k++) numr *= t1;
        for (int k = 0; k < 8; k++) numr *= t2;
        cd den = 1.0;
        for (int j = 0; j < 16; j++)
            if (j != i) den *= (cd(1.0, 0.0) - pd[j] * inv);
        cd r2 = 2.0 * numr / den;             // conjugate pair folded
        if (n < NP) {
            double a1 = 2.0 * pd[i].real();
            double a2 = -std::norm(pd[i]);
            C.a1[n] = (float)a1; C.a2[n] = (float)a2;
            C.b0[n] = (float)r2.real();
            C.b1[n] = (float)(-(r2.real() * pd[i].real() + r2.imag() * pd[i].imag()));
            double M[4] = { a1, a2, 1.0, 0.0 };       // A = [[a1,a2],[1,0]]
            for (int s = 0; s < 4; s++) {             // M0 = A^16
                double q0 = M[0] * M[0] + M[1] * M[2], q1 = M[0] * M[1] + M[1] * M[3];
                double q2 = M[2] * M[0] + M[3] * M[2], q3 = M[2] * M[1] + M[3] * M[3];
                M[0] = q0; M[1] = q1; M[2] = q2; M[3] = q3;
            }
            for (int k = 0; k < 6; k++) {             // lv[k] = M0^(2^k)
                for (int j = 0; j < 4; j++) L.lv[k][n][j] = (float)M[j];
                double q0 = M[0] * M[0] + M[1] * M[2], q1 = M[0] * M[1] + M[1] * M[3];
                double q2 = M[2] * M[0] + M[3] * M[2], q3 = M[2] * M[1] + M[3] * M[3];
                M[0] = q0; M[1] = q1; M[2] = q2; M[3] = q3;
            }
            n++;
        }
    }
    C.c0 = (float)c0.real();
}

extern "C" void kernel_launch(void* const* d_in, const int* in_sizes, int n_in,
                              void* d_out, int out_size, void* d_ws, size_t ws_size,
                              hipStream_t stream) {
    const float* audio = (const float*)d_in[0];
    float* out = (float*)d_out;

    CoeffsS C; LvS L;
    compute_coeffs(C, L);

    // ws: ybuf 33.8MB + mt 8KB
    char* ws = (char*)d_ws;
    size_t o = 0;
    auto alloc = [&](size_t bytes) { size_t r = o; o += (bytes + 255) & ~(size_t)255; return r; };
    float*  ybuf = (float*)(ws + alloc((size_t)NB * LPAD * sizeof(float)));
    float4* mt   = (float4*)(ws + alloc(512 * sizeof(float4)));

    dim3 blk(256), g(NBX, NB);

    k_init   <<<2, 256, 0, stream>>>(mt, L);
    k_full<0><<<g, blk, 0, stream>>>(audio, ybuf, mt, C, L);
    k_full<1><<<g, blk, 0, stream>>>(ybuf, out, mt, C, L);
}

// Round 24
// 64.694 us; speedup vs baseline: 1.1430x; 1.1430x over previous
//
#include <hip/hip_runtime.h>
#include <cmath>
#include <complex>

// sr=16000, band 500-7000, order 8 -> 16 poles = 8 real 2nd-order sections.
#define NB    32
#define LX    262144
#define PAD   51                      // padlen = 3*17
#define LTOT  (LX + 2 * PAD)          // 262246
#define CM    16                      // samples per chunk (= per lane)
#define F_PAD 1946                    // zero-input front pad
#define LPAD  (LTOT + F_PAD)          // 264192 = 258 * 1024 (tile-aligned)
#define TILE  (64 * CM)               // 1024 samples per wave-tile
#define NTILE (LPAD / TILE)           // 258 wave-tiles per row
#define WPB   4                       // wave-tiles per 256-thread block
#define NBX   ((NTILE + WPB - 1) / WPB)  // 65 blocks per row (last: 2 idle waves)
#define NP    8
#define LDSR  17                      // floats per LDS lane-row (gcd(17,32)=1)
#define WIN   14                      // warmup window (chunks) = 224 samples
#define WREG  1280                    // floats per wave LDS region (5120 B)

struct CoeffsS { float a1[NP], a2[NP], b0[NP], b1[NP], c0; };
// lv[k][q] = (A_q^CM)^(2^k) = M0^(2^k), k=0..5 (k_init binary exp); M0 = A^16
struct LvS { float lv[6][NP][4]; };

// wave-private LDS sync: lanes of THIS wave see prior LDS writes after
// lgkmcnt(0) drains (wave64 lockstep; LDS regions are wave-private).
__device__ __forceinline__ void wave_sync() {
    asm volatile("s_waitcnt lgkmcnt(0)" ::: "memory");
}

// ---------------------------------------------------------------------------
// init: build mt[t*8+q] = M0^t (t=0..63) via binary exponentiation.
__global__ void k_init(float4* __restrict__ mt, LvS L) {
    int id = blockIdx.x * 256 + threadIdx.x;
    if (id >= 512) return;
    int t = id >> 3, q = id & 7;
    float m0 = 1.f, m1 = 0.f, m2 = 0.f, m3 = 1.f;
    for (int k = 0; k < 6; k++)
        if ((t >> k) & 1) {
            float a0 = L.lv[k][q][0], a1 = L.lv[k][q][1];
            float a2 = L.lv[k][q][2], a3 = L.lv[k][q][3];
            float n0 = a0 * m0 + a1 * m2, n1 = a0 * m1 + a1 * m3;
            float n2 = a2 * m0 + a3 * m2, n3 = a2 * m1 + a3 * m3;
            m0 = n0; m1 = n1; m2 = n2; m3 = n3;
        }
    mt[id] = make_float4(m0, m1, m2, m3);
}

// ---------------------------------------------------------------------------
// u-loader pass A: chunk c covers t' = c*CM..+CM, real t = t' - F_PAD.
// Safe for negative c (all-pad -> u=0).
__device__ __forceinline__ void load_uA(const float* __restrict__ x,
                                        float base, int c, float (&u)[CM]) {
    int t0 = c * CM - F_PAD;
    if (t0 >= PAD && t0 + CM <= PAD + LX) {
        const float* xs = x + (t0 - PAD);
#pragma unroll
        for (int m = 0; m < CM / 4; m++) {
            float4 v = *reinterpret_cast<const float4*>(xs + 4 * m);
            u[4 * m] = v.x - base; u[4 * m + 1] = v.y - base;
            u[4 * m + 2] = v.z - base; u[4 * m + 3] = v.w - base;
        }
    } else {
#pragma unroll
        for (int i = 0; i < CM; i++) {
            int t = t0 + i;
            float uu;
            if (t < 0) uu = 0.f;                        // front pad
            else {
                float e;
                if (t < PAD)            e = 2.0f * x[0] - x[PAD - t];
                else if (t < PAD + LX)  e = x[t - PAD];
                else                    e = 2.0f * x[LX - 1] - x[2 * LX + PAD - 2 - t];
                uu = e - base;
            }
            u[i] = uu;
        }
    }
}

// u-loader pass B: chunk c from reversed-y buffer minus base; c<0 -> u=0.
__device__ __forceinline__ void load_uB(const float* __restrict__ yb,
                                        float base, int c, float (&u)[CM]) {
    if (c < 0) {
#pragma unroll
        for (int i = 0; i < CM; i++) u[i] = 0.f;
        return;
    }
    const float* ys = yb + (size_t)c * CM;
#pragma unroll
    for (int m = 0; m < CM / 4; m++) {
        float4 v = *reinterpret_cast<const float4*>(ys + 4 * m);
        u[4 * m] = v.x - base; u[4 * m + 1] = v.y - base;
        u[4 * m + 2] = v.z - base; u[4 * m + 3] = v.w - base;
    }
}

// local chunk recurrence from zero state
__device__ __forceinline__ void local_states(const float (&u)[CM], const CoeffsS& C,
                                             float (&w1)[NP], float (&w2)[NP]) {
#pragma unroll
    for (int q = 0; q < NP; q++) { w1[q] = 0.f; w2[q] = 0.f; }
#pragma unroll
    for (int i = 0; i < CM; i++) {
        float uu = u[i];
#pragma unroll
        for (int q = 0; q < NP; q++) {
            float wt = fmaf(C.a1[q], w1[q], fmaf(C.a2[q], w2[q], uu));
            w2[q] = w1[q]; w1[q] = wt;
        }
    }
}

// pack per-lane chunk states: sc4[p*80+j] = (w1[2p],w2[2p],w1[2p+1],w2[2p+1])
__device__ __forceinline__ void pack_states(float4* sc4, int j,
                                            const float (&w1)[NP], const float (&w2)[NP]) {
#pragma unroll
    for (int p = 0; p < 4; p++)
        sc4[p * 80 + j] = make_float4(w1[2 * p], w2[2 * p], w1[2 * p + 1], w2[2 * p + 1]);
}

// ---------------------------------------------------------------------------
// One filtfilt direction; 4 independent wave-tiles per 256-thread block,
// wave-private LDS + waitcnt-only sync (no inter-wave coupling).
// PASS 0: in=audio -> ybuf reversed.  PASS 1: in=ybuf -> out (rev+trim).
template <int PASS>
__global__ __launch_bounds__(256) void k_full(const float* __restrict__ in,
                                              float* __restrict__ outp,
                                              const float4* __restrict__ mt,
                                              CoeffsS C) {
    __shared__ __align__(16) float lds[WPB * WREG];   // 20480 B
    int tid = threadIdx.x, wv = tid >> 6, l = tid & 63;
    int ttx = blockIdx.x * WPB + wv, b = blockIdx.y;
    if (ttx >= NTILE) return;                          // tail block: idle waves
    int c = ttx * 64 + l;
    float* wlds = lds + wv * WREG;
    float4* sc4 = reinterpret_cast<float4*>(wlds);    // 320 float4 = 5120 B

    const float* x = in + (size_t)b * (PASS == 0 ? LX : LPAD);
    float base = (PASS == 0) ? (2.0f * x[0] - x[PAD]) : x[0];

    // ---- warmup: lanes<WIN compute chunk ttx*64-WIN+l (prev tile tail) ----
    if (l < WIN) {
        float uw[CM];
        int cw = ttx * 64 - WIN + l;
        if (PASS == 0) load_uA(x, base, cw, uw);
        else           load_uB(x, base, cw, uw);
        float w1[NP], w2[NP];
        local_states(uw, C, w1, w2);
        pack_states(sc4, l, w1, w2);
    }

    // ---- primary chunk ----
    float u[CM];
    if (PASS == 0) load_uA(x, base, c, u);
    else           load_uB(x, base, c, u);
    float w1[NP], w2[NP];
    local_states(u, C, w1, w2);
    pack_states(sc4, WIN + l, w1, w2);
    wave_sync();

    // ---- window combine: entry = sum_{k=1..WIN} M0^(k-1) f[WIN+l-k] ----
    float e1[NP], e2[NP];
#pragma unroll
    for (int q = 0; q < NP; q++) { e1[q] = 0.f; e2[q] = 0.f; }
#pragma unroll
    for (int k = 1; k <= WIN; k++) {
#pragma unroll
        for (int p = 0; p < 4; p++) {
            float4 f = sc4[p * 80 + WIN + l - k];
            float4 ma = mt[(k - 1) * NP + 2 * p];
            float4 mb = mt[(k - 1) * NP + 2 * p + 1];
            e1[2 * p]     = fmaf(ma.x, f.x, fmaf(ma.y, f.y, e1[2 * p]));
            e2[2 * p]     = fmaf(ma.z, f.x, fmaf(ma.w, f.y, e2[2 * p]));
            e1[2 * p + 1] = fmaf(mb.x, f.z, fmaf(mb.y, f.w, e1[2 * p + 1]));
            e2[2 * p + 1] = fmaf(mb.z, f.z, fmaf(mb.w, f.w, e2[2 * p + 1]));
        }
    }

    // ---- replay u -> y with entry state (registers) ----
#pragma unroll
    for (int q = 0; q < NP; q++) { w1[q] = e1[q]; w2[q] = e2[q]; }
#pragma unroll
    for (int i = 0; i < CM; i++) {
        float uu = u[i];
        float y = C.c0 * uu;
#pragma unroll
        for (int q = 0; q < NP; q++) {
            float wt = fmaf(C.a1[q], w1[q], fmaf(C.a2[q], w2[q], uu));
            y = fmaf(C.b0[q], wt, fmaf(C.b1[q], w1[q], y));
            w2[q] = w1[q]; w1[q] = wt;
        }
        u[i] = y;                          // u now holds y
    }

    // ---- stage y to LDS (stride-17, r17-verified); store ----
    wave_sync();                           // combine reads done before overwrite
#pragma unroll
    for (int i = 0; i < CM; i++) wlds[l * LDSR + i] = u[i];
    wave_sync();

    if (PASS == 0) {
        // coalesced REVERSED store of this tile's 1024 samples (r17-verified)
        float4* yb4 = reinterpret_cast<float4*>(
            outp + (size_t)b * LPAD + (size_t)(NTILE - 1 - ttx) * TILE);
#pragma unroll
        for (int k = 0; k < 4; k++) {
            int o4 = l + 64 * k;               // 0..255
            int ts = 63 - (o4 >> 2);
            int ih = 15 - 4 * (o4 & 3);
            const float* r = &wlds[ts * LDSR];
            yb4[o4] = make_float4(r[ih], r[ih - 1], r[ih - 2], r[ih - 3]);
        }
    } else {
        // out[j] = y2[s], j = (LTOT-1-PAD) - s  (un-reverse + trim, r17-verified)
        float* ob = outp + (size_t)b * LX;
        int J0 = (LTOT - 1 - PAD) - ttx * TILE;
#pragma unroll
        for (int it = 0; it < CM; it++) {
            int o = it * 64 + l;
            int j = J0 - o;
            if (j >= 0 && j < LX)
                ob[j] = wlds[(o >> 4) * LDSR + (o & 15)];
        }
    }
}

// ---------------------------------------------------------------------------
// Host: scipy butter(8,[500,7000]/8000,'bandpass') -> real 2nd-order sections
// + chunk-transition (A^16) power levels (f64, cast to f32).
static void compute_coeffs(CoeffsS& C, LvS& L) {
    using cd = std::complex<double>;
    const int N = 8;
    const double sr = 16000.0, lo = 500.0, hi = 7000.0, fs = 2.0;
    double w0 = 2.0 * fs * std::tan(M_PI * (2.0 * lo / sr) / fs);
    double w1 = 2.0 * fs * std::tan(M_PI * (2.0 * hi / sr) / fs);
    double bw = w1 - w0, wo = std::sqrt(w0 * w1);
    cd pbp[16];
    for (int k = 0; k < N; k++) {
        int m = -N + 1 + 2 * k;
        cd pl = -std::exp(cd(0.0, M_PI * m / (2.0 * N)));
        pl *= bw / 2.0;
        cd s = std::sqrt(pl * pl - cd(wo * wo, 0.0));
        pbp[k] = pl + s; pbp[k + N] = pl - s;
    }
    double kbp = std::pow(bw, (double)N);
    const double fs2 = 4.0;
    cd pd[16], denom = 1.0;
    for (int i = 0; i < 16; i++) {
        pd[i] = (cd(fs2, 0.0) + pbp[i]) / (cd(fs2, 0.0) - pbp[i]);
        denom *= (cd(fs2, 0.0) - pbp[i]);
    }
    double kd = kbp * std::real(cd(std::pow(fs2, 8.0), 0.0) / denom);
    cd prodp = 1.0;
    for (int i = 0; i < 16; i++) prodp *= pd[i];
    cd c0 = cd(kd, 0.0) / prodp;
    int n = 0;
    for (int i = 0; i < 16; i++) {
        if (pd[i].imag() <= 0.0) continue;
        cd inv = 1.0 / pd[i];
        cd t1 = cd(1.0, 0.0) - inv, t2 = cd(1.0, 0.0) + inv;
        cd numr = cd(kd, 0.0);
        for (int k = 0; k < 8; k++) numr *= t1;
        for (int k = 0; k < 8; k++) numr *= t2;
        cd den = 1.0;
        for (int j = 0; j < 16; j++)
            if (j != i) den *= (cd(1.0, 0.0) - pd[j] * inv);
        cd r2 = 2.0 * numr / den;             // conjugate pair folded
        if (n < NP) {
            double a1 = 2.0 * pd[i].real();
            double a2 = -std::norm(pd[i]);
            C.a1[n] = (float)a1; C.a2[n] = (float)a2;
            C.b0[n] = (float)r2.real();
            C.b1[n] = (float)(-(r2.real() * pd[i].real() + r2.imag() * pd[i].imag()));
            double M[4] = { a1, a2, 1.0, 0.0 };       // A = [[a1,a2],[1,0]]
            for (int s = 0; s < 4; s++) {             // M0 = A^16
                double q0 = M[0] * M[0] + M[1] * M[2], q1 = M[0] * M[1] + M[1] * M[3];
                double q2 = M[2] * M[0] + M[3] * M[2], q3 = M[2] * M[1] + M[3] * M[3];
                M[0] = q0; M[1] = q1; M[2] = q2; M[3] = q3;
            }
            for (int k = 0; k < 6; k++) {             // lv[k] = M0^(2^k)
                for (int j = 0; j < 4; j++) L.lv[k][n][j] = (float)M[j];
                double q0 = M[0] * M[0] + M[1] * M[2], q1 = M[0] * M[1] + M[1] * M[3];
                double q2 = M[2] * M[0] + M[3] * M[2], q3 = M[2] * M[1] + M[3] * M[3];
                M[0] = q0; M[1] = q1; M[2] = q2; M[3] = q3;
            }
            n++;
        }
    }
    C.c0 = (float)c0.real();
}

extern "C" void kernel_launch(void* const* d_in, const int* in_sizes, int n_in,
                              void* d_out, int out_size, void* d_ws, size_t ws_size,
                              hipStream_t stream) {
    const float* audio = (const float*)d_in[0];
    float* out = (float*)d_out;

    CoeffsS C; LvS L;
    compute_coeffs(C, L);

    // ws: ybuf 33.8MB + mt 8KB
    char* ws = (char*)d_ws;
    size_t o = 0;
    auto alloc = [&](size_t bytes) { size_t r = o; o += (bytes + 255) & ~(size_t)255; return r; };
    float*  ybuf = (float*)(ws + alloc((size_t)NB * LPAD * sizeof(float)));
    float4* mt   = (float4*)(ws + alloc(512 * sizeof(float4)));

    dim3 blk(256), g(NBX, NB);

    k_init   <<<2, 256, 0, stream>>>(mt, L);
    k_full<0><<<g, blk, 0, stream>>>(audio, ybuf, mt, C);
    k_full<1><<<g, blk, 0, stream>>>(ybuf, out, mt, C);
}